// Round 18
// baseline (772.720 us; speedup 1.0000x reference)
//
#include <hip/hip_runtime.h>
#include <stdint.h>

typedef __attribute__((ext_vector_type(4))) int iv4;      // 4 VGPRs (16B)
typedef __attribute__((ext_vector_type(16))) char i8x16;

#define BM 256
#define BN 256
#define BKB 128   // K bytes per tile (i8); half-tile = [128 rows][128B] = 16KB

// ---- activation quantization: one block per row, per-row scale ----
__global__ __launch_bounds__(256) void quant_act(const float* __restrict__ in,
                                                 signed char* __restrict__ out,
                                                 float* __restrict__ s_a,
                                                 int K) {
  const int row = blockIdx.x;
  const int t = threadIdx.x;
  const float* a = in + (long)row * K;
  float4 v[4];
#pragma unroll
  for (int i = 0; i < 4; ++i)
    v[i] = reinterpret_cast<const float4*>(a)[t * 4 + i];
  float m = 0.f;
#pragma unroll
  for (int i = 0; i < 4; ++i) {
    m = fmaxf(m, fmaxf(fmaxf(fabsf(v[i].x), fabsf(v[i].y)),
                       fmaxf(fabsf(v[i].z), fabsf(v[i].w))));
  }
#pragma unroll
  for (int off = 32; off; off >>= 1) m = fmaxf(m, __shfl_xor(m, off));
  __shared__ float wmax[4];
  const int lane = t & 63, wvq = t >> 6;
  if (lane == 0) wmax[wvq] = m;
  __syncthreads();
  m = fmaxf(fmaxf(wmax[0], wmax[1]), fmaxf(wmax[2], wmax[3]));
  const float inv = m > 0.f ? 127.f / m : 0.f;
  if (t == 0) s_a[row] = m > 0.f ? m / 127.f : 0.f;
  i8x16 q;
#pragma unroll
  for (int i = 0; i < 4; ++i) {
    q[i * 4 + 0] = (char)(int)rintf(fminf(fmaxf(v[i].x * inv, -127.f), 127.f));
    q[i * 4 + 1] = (char)(int)rintf(fminf(fmaxf(v[i].y * inv, -127.f), 127.f));
    q[i * 4 + 2] = (char)(int)rintf(fminf(fmaxf(v[i].z * inv, -127.f), 127.f));
    q[i * 4 + 3] = (char)(int)rintf(fminf(fmaxf(v[i].w * inv, -127.f), 127.f));
  }
  reinterpret_cast<i8x16*>(out + (long)row * K)[t] = q;
}

// ---- weight pack: int32 (|v|<=127) -> int8 ----
__global__ void pack_w(const int* __restrict__ in, signed char* __restrict__ out,
                       long n16) {
  long stride = (long)gridDim.x * blockDim.x;
  for (long i = (long)blockIdx.x * blockDim.x + threadIdx.x; i < n16; i += stride) {
    i8x16 q;
#pragma unroll
    for (int c = 0; c < 4; ++c) {
      int4 w = reinterpret_cast<const int4*>(in)[i * 4 + c];
      q[c * 4 + 0] = (char)w.x;
      q[c * 4 + 1] = (char)w.y;
      q[c * 4 + 2] = (char)w.z;
      q[c * 4 + 3] = (char)w.w;
    }
    reinterpret_cast<i8x16*>(out)[i] = q;
  }
}

#define GLDS16(g, l)                                                          \
  __builtin_amdgcn_global_load_lds(                                           \
      (const __attribute__((address_space(1))) unsigned int*)(g),             \
      (__attribute__((address_space(3))) unsigned int*)(l), 16, 0, 0)

// PLAIN C++ LDS read (16B aligned -> ds_read_b128). Unlike the R5-R17 asm
// reads, plain loads are NOT scheduler region boundaries, so the compiler
// can interleave reads / address VALU / GLDS issue within a phase and emit
// counted lgkmcnt - the mechanism behind m201's ~490-cyc/tile overhead vs
// our asm-rigid 2470. Buffer indices are fully STATIC (2x unroll), so
// SIInsertWaitcnts can disambiguate As[0]/As[1] vs the outstanding LDS-DMA
// writes and does NOT need conservative vmcnt(0) drains (the R4 failure was
// runtime cur indexing).
#define LDP(p, OFF) (*reinterpret_cast<const iv4*>((p) + (OFF)))

#define BAR __builtin_amdgcn_s_barrier()
#define SCHEDB __builtin_amdgcn_sched_barrier(0)
#define LGKM_0 asm volatile("s_waitcnt lgkmcnt(0)")
#define VMC_4 asm volatile("s_waitcnt vmcnt(4)")

// 16 MFMAs for C-quadrant (I0, J0): sum over ks into same acc (K-recipe)
#define PH_MFMA(AF, BQ, I0, J0)                                               \
  _Pragma("unroll") for (int i = 0; i < 4; ++i)                               \
    _Pragma("unroll") for (int jj = 0; jj < 2; ++jj)                          \
      _Pragma("unroll") for (int ks = 0; ks < 2; ++ks)                        \
        acc[(I0) + i][(J0) + jj] = __builtin_amdgcn_mfma_i32_16x16x64_i8(     \
            AF[i][ks], BQ[jj][ks], acc[(I0) + i][(J0) + jj], 0, 0, 0)

// 256x256 int8 GEMM - R16's m201 choreography with compiler-scheduled
// phase interiors (plain LDS reads). Structure per K-tile: 4 C-quadrant
// phases (A0B0, A0B1, A1B1, A1B0), reads 12/4/8/0 pre-barrier, lgkmcnt(0)
// post-barrier (load-bearing cross-wave WAR at ph2/ph3), 16 MFMA in
// setprio(1), one half-tile staged per phase ~1.75 tiles ahead, ONE
// vmcnt(4) per K-tile. 8-slot/row XOR swizzle (phys = logical^((row>>1)&7)),
// write-side inverse-permuted source column: 0 bank conflicts (measured).
__global__ __launch_bounds__(512, 2) void gemm256_pl(
    const signed char* __restrict__ A,   // [M][K] i8 (row-quantized)
    const signed char* __restrict__ W,   // [N][K] i8
    const float* __restrict__ s_a,       // [M] activation row scales
    const float* __restrict__ scale,     // [N] weight col scales
    const float* __restrict__ bias,      // [N]
    float* __restrict__ C,               // [M][N] f32
    int M, int N, int K) {
  __shared__ __align__(16) signed char As[2][2][128 * 128];  // 64 KiB
  __shared__ __align__(16) signed char Bs[2][2][128 * 128];  // 64 KiB

  const int tid = threadIdx.x;
  const int lane = tid & 63;
  const int wv = tid >> 6;       // 0..7
  const int wm = wv >> 2;        // 0..1  (wave rows: LDS half wm)
  const int wn = wv & 3;         // 0..3  (wave cols: 64 within B-half wn>>1)

  const int nwg = gridDim.x;
  const int bid = blockIdx.x;
  const int wg = ((nwg & 7) == 0) ? ((bid & 7) * (nwg >> 3) + (bid >> 3)) : bid;
  const int mT = M / BM;
  const int bm = wg % mT;        // M-fast: neighbors share W panel
  const int bn = wg / mT;

  const long aRow0 = (long)bm * BM;
  const long wRow0 = (long)bn * BN;

  // ---- staging: issue q in {0,1}; wave wv covers 1KB per issue.
  // lane l -> linear LDS slot (l&7) at row (q*8+wv)*8+(l>>3); it must carry
  // logical slot (l&7)^((row>>1)&7) = (l&7)^(((wv&1)<<2)|(l>>4)).
  const int sRow0 = (0 * 8 + wv) * 8 + (lane >> 3);
  const int sRow1 = (1 * 8 + wv) * 8 + (lane >> 3);
  const int srcslot = (lane & 7) ^ (((wv & 1) << 2) | (lane >> 4));
  const signed char* aS0 = A + (aRow0 + sRow0) * (long)K + srcslot * 16;
  const signed char* aS1 = A + (aRow0 + sRow1) * (long)K + srcslot * 16;
  const signed char* wS0 = W + (wRow0 + sRow0) * (long)K + srcslot * 16;
  const signed char* wS1 = W + (wRow0 + sRow1) * (long)K + srcslot * 16;
  const long AH = 128 * (long)K;           // second-half source row offset
  const int d0 = (0 * 8 + wv) * 1024 + lane * 16;
  const int d1 = (1 * 8 + wv) * 1024 + lane * 16;

  // ---- read base: row (l&15), phys slot ((l>>4)^((l>>1)&7)); ks1 = ^64.
  const int rdLane = (lane & 15) * 128 + (((lane >> 4) ^ ((lane >> 1) & 7)) * 16);
  const int rdB_off = (wn & 1) * 8192;     // wave's 64 B-rows within its half

  iv4 acc[8][4] = {};
  iv4 aF[4][2], bQ0[2][2], bQ1[2][2];

  const int nk = K / BKB;   // 32

  // ---- prologue: t0 all 4 halves -> buf0; t1.B1, t1.A0 -> buf1
  GLDS16(aS0, &As[0][0][d0]);           GLDS16(aS1, &As[0][0][d1]);
  GLDS16(aS0 + AH, &As[0][1][d0]);      GLDS16(aS1 + AH, &As[0][1][d1]);
  GLDS16(wS0, &Bs[0][0][d0]);           GLDS16(wS1, &Bs[0][0][d1]);
  GLDS16(wS0 + AH, &Bs[0][1][d0]);      GLDS16(wS1 + AH, &Bs[0][1][d1]);
  GLDS16(wS0 + AH + BKB, &Bs[1][1][d0]); GLDS16(wS1 + AH + BKB, &Bs[1][1][d1]);
  GLDS16(aS0 + BKB, &As[1][0][d0]);     GLDS16(aS1 + BKB, &As[1][0][d1]);
  VMC_4;   // 12 issued -> retire 8 oldest = all of t0; t1.{B1,A0} in flight
  BAR;

#define TILE_BODY(CUR, NXT, KO1, KO2)                                         \
  {                                                                           \
    SCHEDB; /* pin tile boundary: no reads hoist above the publish BAR */     \
    const signed char* pAk0 = &As[CUR][wm][rdLane];                           \
    const signed char* pAk1 = &As[CUR][wm][rdLane ^ 64];                      \
    const signed char* pBk0 = &Bs[CUR][wn >> 1][rdB_off + rdLane];            \
    const signed char* pBk1 = &Bs[CUR][wn >> 1][rdB_off + (rdLane ^ 64)];     \
    /* ph1 (A0,B0): 12 reads; stage A1(t+1) */                                \
    bQ0[0][0] = LDP(pBk0, 0);    bQ0[0][1] = LDP(pBk1, 0);                    \
    bQ0[1][0] = LDP(pBk0, 2048); bQ0[1][1] = LDP(pBk1, 2048);                 \
    aF[0][0] = LDP(pAk0, 0);     aF[0][1] = LDP(pAk1, 0);                     \
    aF[1][0] = LDP(pAk0, 2048);  aF[1][1] = LDP(pAk1, 2048);                  \
    aF[2][0] = LDP(pAk0, 4096);  aF[2][1] = LDP(pAk1, 4096);                  \
    aF[3][0] = LDP(pAk0, 6144);  aF[3][1] = LDP(pAk1, 6144);                  \
    GLDS16(aS0 + AH + (KO1), &As[NXT][1][d0]);                                \
    GLDS16(aS1 + AH + (KO1), &As[NXT][1][d1]);                                \
    BAR;                                                                      \
    LGKM_0;                                                                   \
    __builtin_amdgcn_s_setprio(1);                                            \
    PH_MFMA(aF, bQ0, 0, 0);                                                   \
    __builtin_amdgcn_s_setprio(0);                                            \
    BAR;                                                                      \
    /* ph2 (A0,B1): 4 reads; stage B0(t+1) */                                 \
    bQ1[0][0] = LDP(pBk0, 4096); bQ1[0][1] = LDP(pBk1, 4096);                 \
    bQ1[1][0] = LDP(pBk0, 6144); bQ1[1][1] = LDP(pBk1, 6144);                 \
    GLDS16(wS0 + (KO1), &Bs[NXT][0][d0]);                                     \
    GLDS16(wS1 + (KO1), &Bs[NXT][0][d1]);                                     \
    BAR;                                                                      \
    LGKM_0;                                                                   \
    __builtin_amdgcn_s_setprio(1);                                            \
    PH_MFMA(aF, bQ1, 0, 2);                                                   \
    __builtin_amdgcn_s_setprio(0);                                            \
    BAR;                                                                      \
    /* ph3 (A1,B1): 8 reads; stage B1(t+2) */                                 \
    aF[0][0] = LDP(pAk0, 8192);  aF[0][1] = LDP(pAk1, 8192);                  \
    aF[1][0] = LDP(pAk0, 10240); aF[1][1] = LDP(pAk1, 10240);                 \
    aF[2][0] = LDP(pAk0, 12288); aF[2][1] = LDP(pAk1, 12288);                 \
    aF[3][0] = LDP(pAk0, 14336); aF[3][1] = LDP(pAk1, 14336);                 \
    GLDS16(wS0 + AH + (KO2), &Bs[CUR][1][d0]);                                \
    GLDS16(wS1 + AH + (KO2), &Bs[CUR][1][d1]);                                \
    BAR;                                                                      \
    LGKM_0;                                                                   \
    __builtin_amdgcn_s_setprio(1);                                            \
    PH_MFMA(aF, bQ1, 4, 2);                                                   \
    __builtin_amdgcn_s_setprio(0);                                            \
    BAR;                                                                      \
    /* ph4 (A1,B0): 0 reads; stage A0(t+2); vmcnt(4) publishes all of t+1 */  \
    GLDS16(aS0 + (KO2), &As[CUR][0][d0]);                                     \
    GLDS16(aS1 + (KO2), &As[CUR][0][d1]);                                     \
    __builtin_amdgcn_s_setprio(1);                                            \
    PH_MFMA(aF, bQ0, 4, 0);                                                   \
    __builtin_amdgcn_s_setprio(0);                                            \
    VMC_4;                                                                    \
    BAR;                                                                      \
  }

  for (int kt = 0; kt < nk; kt += 2) {
    const long ka1 = (long)(kt + 1) * BKB;                        // < nk
    const long ka2 = (kt + 2 < nk) ? (long)(kt + 2) * BKB : 0;    // wrap ok
    const long kb1 = ka2;
    const long kb2 = (kt + 3 < nk) ? (long)(kt + 3) * BKB : 0;
    TILE_BODY(0, 1, ka1, ka2);
    TILE_BODY(1, 0, kb1, kb2);
  }
#undef TILE_BODY

  // epilogue: C/D frag layout col=lane&15, row=(lane>>4)*4+v (dtype-indep)
  const long col0 = wRow0 + wn * 64 + (lane & 15);
  float scl[4], bs[4];
#pragma unroll
  for (int j = 0; j < 4; ++j) {
    scl[j] = scale[col0 + j * 16];
    bs[j] = bias[col0 + j * 16];
  }
  const long row0 = aRow0 + wm * 128 + ((lane >> 4) << 2);
#pragma unroll
  for (int i = 0; i < 8; ++i) {
#pragma unroll
    for (int v = 0; v < 4; ++v) {
      const float rs = s_a[row0 + i * 16 + v];
      float* cp = C + (row0 + i * 16 + v) * (long)N + col0;
#pragma unroll
      for (int j = 0; j < 4; ++j)
        cp[j * 16] = (float)acc[i][j][v] * (rs * scl[j]) + bs[j];
    }
  }
}

// correctness-only fallback (reads original fp32/int32 inputs)
__global__ void naive_w8a16(const float* __restrict__ inp,
                            const int* __restrict__ qw,
                            const float* __restrict__ scale,
                            const float* __restrict__ bias,
                            float* __restrict__ out, long M, long N, long K) {
  long idx = (long)blockIdx.x * blockDim.x + threadIdx.x;
  if (idx >= M * N) return;
  long col = idx % N, row = idx / N;
  const float* a = inp + row * K;
  const int* w = qw + col * K;
  float s = 0.f;
  for (long k = 0; k < K; k += 4) {
    float4 av = *reinterpret_cast<const float4*>(&a[k]);
    int4 wv = *reinterpret_cast<const int4*>(&w[k]);
    s += av.x * (float)wv.x + av.y * (float)wv.y + av.z * (float)wv.z +
         av.w * (float)wv.w;
  }
  out[idx] = s * scale[col] + bias[col];
}

extern "C" void kernel_launch(void* const* d_in, const int* in_sizes, int n_in,
                              void* d_out, int out_size, void* d_ws,
                              size_t ws_size, hipStream_t stream) {
  const float* inp = (const float*)d_in[0];   // [B,S,D_IN] f32
  const int* qw = (const int*)d_in[1];        // [D_OUT,D_IN] i32
  const float* scale = (const float*)d_in[2]; // [D_OUT]
  const float* bias = (const float*)d_in[3];  // [D_OUT]
  float* out = (float*)d_out;                 // [B,S,D_OUT] f32

  const long N = in_sizes[2];                 // 16384
  const long K = (long)in_sizes[1] / N;       // 4096
  const long M = (long)in_sizes[0] / K;       // 8192

  const size_t aB = (size_t)M * K;            // 32 MiB (i8)
  const size_t wB = (size_t)N * K;            // 64 MiB (i8)
  const size_t sB = (size_t)M * 4;            // row scales
  const long nk = K / BKB;

  if (ws_size >= aB + wB + sB && (M % BM) == 0 && (N % BN) == 0 &&
      K == 4096 && nk >= 4 && (nk % 2) == 0) {
    signed char* Ai8 = (signed char*)d_ws;
    signed char* Wi8 = (signed char*)d_ws + aB;
    float* sA = (float*)((char*)d_ws + aB + wB);
    quant_act<<<(int)M, 256, 0, stream>>>(inp, Ai8, sA, (int)K);
    pack_w<<<2048, 256, 0, stream>>>(qw, Wi8, N * K / 16);
    const int nwg = (int)((M / BM) * (N / BN));  // 2048
    gemm256_pl<<<nwg, 512, 0, stream>>>(Ai8, Wi8, sA, scale, bias, out,
                                        (int)M, (int)N, (int)K);
  } else {
    long total = M * N;
    naive_w8a16<<<(int)((total + 255) / 256), 256, 0, stream>>>(
        inp, qw, scale, bias, out, M, N, K);
  }
}

// Round 19
// 699.752 us; speedup vs baseline: 1.1043x; 1.1043x over previous
//
#include <hip/hip_runtime.h>
#include <stdint.h>

typedef __attribute__((ext_vector_type(4))) int iv4;      // 4 VGPRs (16B)
typedef __attribute__((ext_vector_type(16))) char i8x16;

#define BM 256
#define BN 256
#define BKB 128   // K bytes per tile (i8); half-tile = [128 rows][128B] = 16KB

// ---- activation quantization: one block per row, per-row scale ----
__global__ __launch_bounds__(256) void quant_act(const float* __restrict__ in,
                                                 signed char* __restrict__ out,
                                                 float* __restrict__ s_a,
                                                 int K) {
  const int row = blockIdx.x;
  const int t = threadIdx.x;
  const float* a = in + (long)row * K;
  float4 v[4];
#pragma unroll
  for (int i = 0; i < 4; ++i)
    v[i] = reinterpret_cast<const float4*>(a)[t * 4 + i];
  float m = 0.f;
#pragma unroll
  for (int i = 0; i < 4; ++i) {
    m = fmaxf(m, fmaxf(fmaxf(fabsf(v[i].x), fabsf(v[i].y)),
                       fmaxf(fabsf(v[i].z), fabsf(v[i].w))));
  }
#pragma unroll
  for (int off = 32; off; off >>= 1) m = fmaxf(m, __shfl_xor(m, off));
  __shared__ float wmax[4];
  const int lane = t & 63, wvq = t >> 6;
  if (lane == 0) wmax[wvq] = m;
  __syncthreads();
  m = fmaxf(fmaxf(wmax[0], wmax[1]), fmaxf(wmax[2], wmax[3]));
  const float inv = m > 0.f ? 127.f / m : 0.f;
  if (t == 0) s_a[row] = m > 0.f ? m / 127.f : 0.f;
  i8x16 q;
#pragma unroll
  for (int i = 0; i < 4; ++i) {
    q[i * 4 + 0] = (char)(int)rintf(fminf(fmaxf(v[i].x * inv, -127.f), 127.f));
    q[i * 4 + 1] = (char)(int)rintf(fminf(fmaxf(v[i].y * inv, -127.f), 127.f));
    q[i * 4 + 2] = (char)(int)rintf(fminf(fmaxf(v[i].z * inv, -127.f), 127.f));
    q[i * 4 + 3] = (char)(int)rintf(fminf(fmaxf(v[i].w * inv, -127.f), 127.f));
  }
  reinterpret_cast<i8x16*>(out + (long)row * K)[t] = q;
}

// ---- weight pack: int32 (|v|<=127) -> int8 ----
__global__ void pack_w(const int* __restrict__ in, signed char* __restrict__ out,
                       long n16) {
  long stride = (long)gridDim.x * blockDim.x;
  for (long i = (long)blockIdx.x * blockDim.x + threadIdx.x; i < n16; i += stride) {
    i8x16 q;
#pragma unroll
    for (int c = 0; c < 4; ++c) {
      int4 w = reinterpret_cast<const int4*>(in)[i * 4 + c];
      q[c * 4 + 0] = (char)w.x;
      q[c * 4 + 1] = (char)w.y;
      q[c * 4 + 2] = (char)w.z;
      q[c * 4 + 3] = (char)w.w;
    }
    reinterpret_cast<i8x16*>(out)[i] = q;
  }
}

#define GLDS16(g, l)                                                          \
  __builtin_amdgcn_global_load_lds(                                           \
      (const __attribute__((address_space(1))) unsigned int*)(g),             \
      (__attribute__((address_space(3))) unsigned int*)(l), 16, 0, 0)

// Inline-asm ds_read_b128 (R16-proven: beats both compiler-scheduled plain
// loads (R18, +8%) and every other wait regime tried). rule #18 discipline.
typedef __attribute__((address_space(3))) const signed char lds_c8;

template <int OFF>
__device__ __forceinline__ iv4 ldsb128(lds_c8* p) {
  iv4 r;
  asm volatile("ds_read_b128 %0, %1 offset:%2" : "=v"(r) : "v"(p), "i"(OFF));
  return r;
}

#define BAR __builtin_amdgcn_s_barrier()
#define SCHEDB __builtin_amdgcn_sched_barrier(0)
#define LGKM_0 asm volatile("s_waitcnt lgkmcnt(0)")
#define LGKM_8 asm volatile("s_waitcnt lgkmcnt(8)")
#define VMC_2 asm volatile("s_waitcnt vmcnt(2)")

// 16 MFMAs for C-quadrant (I0, J0): sum over ks into same acc (K-recipe)
#define PH_MFMA(AF, BQ, I0, J0)                                               \
  _Pragma("unroll") for (int i = 0; i < 4; ++i)                               \
    _Pragma("unroll") for (int jj = 0; jj < 2; ++jj)                          \
      _Pragma("unroll") for (int ks = 0; ks < 2; ++ks)                        \
        acc[(I0) + i][(J0) + jj] = __builtin_amdgcn_mfma_i32_16x16x64_i8(     \
            AF[i][ks], BQ[jj][ks], acc[(I0) + i][(J0) + jj], 0, 0, 0)

// 256x256 int8 GEMM - R16's m201 4-phase choreography with read/MFMA window
// OVERLAP: the post-MFMA barriers of ph1 and ph2 are removed, so ph2's and
// ph3's read+stage windows execute concurrently with other waves' preceding
// MFMA windows (in R16 the barrier pairs time-separated the LDS and MFMA
// pipes block-wide). Safety ledger (all cross-wave hazards re-derived):
//  - GLDS2 -> Bs[NXT][0]: last readers drained tile t-1 (>=2 barriers) OK
//  - GLDS3 re-rotated to Bs[NXT][1] (1-tile depth, was CUR/t+2): last
//    readers tile t-1 OK -> ph2-post barrier droppable
//  - GLDS4 -> As[CUR][0] races ph3's in-flight rows-64-127 reads -> ph3-post
//    barrier KEPT
//  - tile-top wait becomes vmcnt(2): in-order retirement publishes all of
//    tile t+1 (A1,B0 from ph1/ph2, B1 from ph3, A0 from t-1:ph4); exactly
//    ph4's A0(t+2) pair stays in flight - queue never drains
__global__ __launch_bounds__(512, 2) void gemm256_ov(
    const signed char* __restrict__ A,   // [M][K] i8 (row-quantized)
    const signed char* __restrict__ W,   // [N][K] i8
    const float* __restrict__ s_a,       // [M] activation row scales
    const float* __restrict__ scale,     // [N] weight col scales
    const float* __restrict__ bias,      // [N]
    float* __restrict__ C,               // [M][N] f32
    int M, int N, int K) {
  __shared__ __align__(16) signed char As[2][2][128 * 128];  // 64 KiB
  __shared__ __align__(16) signed char Bs[2][2][128 * 128];  // 64 KiB

  const int tid = threadIdx.x;
  const int lane = tid & 63;
  const int wv = tid >> 6;       // 0..7
  const int wm = wv >> 2;        // 0..1  (wave rows: LDS half wm)
  const int wn = wv & 3;         // 0..3  (wave cols: 64 within B-half wn>>1)

  const int nwg = gridDim.x;
  const int bid = blockIdx.x;
  const int wg = ((nwg & 7) == 0) ? ((bid & 7) * (nwg >> 3) + (bid >> 3)) : bid;
  const int mT = M / BM;
  const int bm = wg % mT;        // M-fast: neighbors share W panel
  const int bn = wg / mT;

  const long aRow0 = (long)bm * BM;
  const long wRow0 = (long)bn * BN;

  // ---- staging: issue q in {0,1}; wave wv covers 1KB per issue.
  // lane l -> linear LDS slot (l&7) at row (q*8+wv)*8+(l>>3); it must carry
  // logical slot (l&7)^((row>>1)&7) = (l&7)^(((wv&1)<<2)|(l>>4)).
  const int sRow0 = (0 * 8 + wv) * 8 + (lane >> 3);
  const int sRow1 = (1 * 8 + wv) * 8 + (lane >> 3);
  const int srcslot = (lane & 7) ^ (((wv & 1) << 2) | (lane >> 4));
  const signed char* aS0 = A + (aRow0 + sRow0) * (long)K + srcslot * 16;
  const signed char* aS1 = A + (aRow0 + sRow1) * (long)K + srcslot * 16;
  const signed char* wS0 = W + (wRow0 + sRow0) * (long)K + srcslot * 16;
  const signed char* wS1 = W + (wRow0 + sRow1) * (long)K + srcslot * 16;
  const long AH = 128 * (long)K;           // second-half source row offset
  const int d0 = (0 * 8 + wv) * 1024 + lane * 16;
  const int d1 = (1 * 8 + wv) * 1024 + lane * 16;

  // ---- read base: row (l&15), phys slot ((l>>4)^((l>>1)&7)); ks1 = ^64.
  const int rdLane = (lane & 15) * 128 + (((lane >> 4) ^ ((lane >> 1) & 7)) * 16);
  const int rdB_off = (wn & 1) * 8192;     // wave's 64 B-rows within its half

  iv4 acc[8][4] = {};
  iv4 aF[4][2], bQ0[2][2], bQ1[2][2];

  const int nk = K / BKB;   // 32

  // ---- prologue: t0 all 4 halves -> buf0; t1.A0 -> buf1 (10 issues)
  GLDS16(aS0, &As[0][0][d0]);           GLDS16(aS1, &As[0][0][d1]);
  GLDS16(aS0 + AH, &As[0][1][d0]);      GLDS16(aS1 + AH, &As[0][1][d1]);
  GLDS16(wS0, &Bs[0][0][d0]);           GLDS16(wS1, &Bs[0][0][d1]);
  GLDS16(wS0 + AH, &Bs[0][1][d0]);      GLDS16(wS1 + AH, &Bs[0][1][d1]);
  GLDS16(aS0 + BKB, &As[1][0][d0]);     GLDS16(aS1 + BKB, &As[1][0][d1]);
  VMC_2;   // retire 8 oldest = all of t0; t1.A0 stays in flight
  BAR;

#define TILE_BODY(CUR, NXT, KO1, KO2)                                         \
  {                                                                           \
    lds_c8* pAk0 = (lds_c8*)&As[CUR][wm][rdLane];                             \
    lds_c8* pAk1 = (lds_c8*)&As[CUR][wm][rdLane ^ 64];                        \
    lds_c8* pBk0 = (lds_c8*)&Bs[CUR][wn >> 1][rdB_off + rdLane];              \
    lds_c8* pBk1 = (lds_c8*)&Bs[CUR][wn >> 1][rdB_off + (rdLane ^ 64)];       \
    /* ph1 (A0,B0): 12 reads; stage A1(t+1) */                                \
    bQ0[0][0] = ldsb128<0>(pBk0);    bQ0[0][1] = ldsb128<0>(pBk1);            \
    bQ0[1][0] = ldsb128<2048>(pBk0); bQ0[1][1] = ldsb128<2048>(pBk1);         \
    aF[0][0] = ldsb128<0>(pAk0);     aF[0][1] = ldsb128<0>(pAk1);             \
    aF[1][0] = ldsb128<2048>(pAk0);  aF[1][1] = ldsb128<2048>(pAk1);          \
    aF[2][0] = ldsb128<4096>(pAk0);  aF[2][1] = ldsb128<4096>(pAk1);          \
    aF[3][0] = ldsb128<6144>(pAk0);  aF[3][1] = ldsb128<6144>(pAk1);          \
    GLDS16(aS0 + AH + (KO1), &As[NXT][1][d0]);                                \
    GLDS16(aS1 + AH + (KO1), &As[NXT][1][d1]);                                \
    LGKM_8; SCHEDB;                                                           \
    BAR;                                                                      \
    LGKM_0; SCHEDB;                                                           \
    __builtin_amdgcn_s_setprio(1);                                            \
    PH_MFMA(aF, bQ0, 0, 0);                                                   \
    __builtin_amdgcn_s_setprio(0);                                            \
    SCHEDB; /* ph1-post barrier DROPPED: ph2 window overlaps MFMA1 */         \
    /* ph2 (A0,B1): 4 reads; stage B0(t+1) */                                 \
    bQ1[0][0] = ldsb128<4096>(pBk0); bQ1[0][1] = ldsb128<4096>(pBk1);         \
    bQ1[1][0] = ldsb128<6144>(pBk0); bQ1[1][1] = ldsb128<6144>(pBk1);         \
    GLDS16(wS0 + (KO1), &Bs[NXT][0][d0]);                                     \
    GLDS16(wS1 + (KO1), &Bs[NXT][0][d1]);                                     \
    BAR;                                                                      \
    LGKM_0; SCHEDB;                                                           \
    __builtin_amdgcn_s_setprio(1);                                            \
    PH_MFMA(aF, bQ1, 0, 2);                                                   \
    __builtin_amdgcn_s_setprio(0);                                            \
    SCHEDB; /* ph2-post barrier DROPPED (GLDS3 now targets NXT region) */     \
    /* ph3 (A1,B1): 8 reads; stage B1(t+1) [re-rotated from t+2] */           \
    aF[0][0] = ldsb128<8192>(pAk0);  aF[0][1] = ldsb128<8192>(pAk1);          \
    aF[1][0] = ldsb128<10240>(pAk0); aF[1][1] = ldsb128<10240>(pAk1);         \
    aF[2][0] = ldsb128<12288>(pAk0); aF[2][1] = ldsb128<12288>(pAk1);         \
    aF[3][0] = ldsb128<14336>(pAk0); aF[3][1] = ldsb128<14336>(pAk1);         \
    GLDS16(wS0 + AH + (KO1), &Bs[NXT][1][d0]);                                \
    GLDS16(wS1 + AH + (KO1), &Bs[NXT][1][d1]);                                \
    BAR;                                                                      \
    LGKM_0; SCHEDB;                                                           \
    __builtin_amdgcn_s_setprio(1);                                            \
    PH_MFMA(aF, bQ1, 4, 2);                                                   \
    __builtin_amdgcn_s_setprio(0);                                            \
    SCHEDB;                                                                   \
    BAR; /* ph3-post KEPT: GLDS4 overwrites As[CUR][0] vs ph3 reads */        \
    /* ph4 (A1,B0): 0 reads; stage A0(t+2); vmcnt(2) publishes t+1 */         \
    GLDS16(aS0 + (KO2), &As[CUR][0][d0]);                                     \
    GLDS16(aS1 + (KO2), &As[CUR][0][d1]);                                     \
    __builtin_amdgcn_s_setprio(1);                                            \
    PH_MFMA(aF, bQ0, 4, 0);                                                   \
    __builtin_amdgcn_s_setprio(0);                                            \
    VMC_2; SCHEDB;                                                            \
    BAR;                                                                      \
  }

  for (int kt = 0; kt < nk; kt += 2) {
    const long ka1 = (long)(kt + 1) * BKB;                        // < nk
    const long ka2 = (kt + 2 < nk) ? (long)(kt + 2) * BKB : 0;    // wrap ok
    const long kb1 = ka2;
    const long kb2 = (kt + 3 < nk) ? (long)(kt + 3) * BKB : 0;
    TILE_BODY(0, 1, ka1, ka2);
    TILE_BODY(1, 0, kb1, kb2);
  }
#undef TILE_BODY

  // epilogue: C/D frag layout col=lane&15, row=(lane>>4)*4+v (dtype-indep)
  const long col0 = wRow0 + wn * 64 + (lane & 15);
  float scl[4], bs[4];
#pragma unroll
  for (int j = 0; j < 4; ++j) {
    scl[j] = scale[col0 + j * 16];
    bs[j] = bias[col0 + j * 16];
  }
  const long row0 = aRow0 + wm * 128 + ((lane >> 4) << 2);
#pragma unroll
  for (int i = 0; i < 8; ++i) {
#pragma unroll
    for (int v = 0; v < 4; ++v) {
      const float rs = s_a[row0 + i * 16 + v];
      float* cp = C + (row0 + i * 16 + v) * (long)N + col0;
#pragma unroll
      for (int j = 0; j < 4; ++j)
        cp[j * 16] = (float)acc[i][j][v] * (rs * scl[j]) + bs[j];
    }
  }
}

// correctness-only fallback (reads original fp32/int32 inputs)
__global__ void naive_w8a16(const float* __restrict__ inp,
                            const int* __restrict__ qw,
                            const float* __restrict__ scale,
                            const float* __restrict__ bias,
                            float* __restrict__ out, long M, long N, long K) {
  long idx = (long)blockIdx.x * blockDim.x + threadIdx.x;
  if (idx >= M * N) return;
  long col = idx % N, row = idx / N;
  const float* a = inp + row * K;
  const int* w = qw + col * K;
  float s = 0.f;
  for (long k = 0; k < K; k += 4) {
    float4 av = *reinterpret_cast<const float4*>(&a[k]);
    int4 wv = *reinterpret_cast<const int4*>(&w[k]);
    s += av.x * (float)wv.x + av.y * (float)wv.y + av.z * (float)wv.z +
         av.w * (float)wv.w;
  }
  out[idx] = s * scale[col] + bias[col];
}

extern "C" void kernel_launch(void* const* d_in, const int* in_sizes, int n_in,
                              void* d_out, int out_size, void* d_ws,
                              size_t ws_size, hipStream_t stream) {
  const float* inp = (const float*)d_in[0];   // [B,S,D_IN] f32
  const int* qw = (const int*)d_in[1];        // [D_OUT,D_IN] i32
  const float* scale = (const float*)d_in[2]; // [D_OUT]
  const float* bias = (const float*)d_in[3];  // [D_OUT]
  float* out = (float*)d_out;                 // [B,S,D_OUT] f32

  const long N = in_sizes[2];                 // 16384
  const long K = (long)in_sizes[1] / N;       // 4096
  const long M = (long)in_sizes[0] / K;       // 8192

  const size_t aB = (size_t)M * K;            // 32 MiB (i8)
  const size_t wB = (size_t)N * K;            // 64 MiB (i8)
  const size_t sB = (size_t)M * 4;            // row scales
  const long nk = K / BKB;

  if (ws_size >= aB + wB + sB && (M % BM) == 0 && (N % BN) == 0 &&
      K == 4096 && nk >= 4 && (nk % 2) == 0) {
    signed char* Ai8 = (signed char*)d_ws;
    signed char* Wi8 = (signed char*)d_ws + aB;
    float* sA = (float*)((char*)d_ws + aB + wB);
    quant_act<<<(int)M, 256, 0, stream>>>(inp, Ai8, sA, (int)K);
    pack_w<<<2048, 256, 0, stream>>>(qw, Wi8, N * K / 16);
    const int nwg = (int)((M / BM) * (N / BN));  // 2048
    gemm256_ov<<<nwg, 512, 0, stream>>>(Ai8, Wi8, sA, scale, bias, out,
                                        (int)M, (int)N, (int)K);
  } else {
    long total = M * N;
    naive_w8a16<<<(int)((total + 255) / 256), 256, 0, stream>>>(
        inp, qw, scale, bias, out, M, N, K);
  }
}